// Round 6
// baseline (506.472 us; speedup 1.0000x reference)
//
#include <hip/hip_runtime.h>
#include <hip/hip_bf16.h>

#define B_ 4096
#define I_ 1024
#define H_ 2048
#define O_ 1024
#define K1 (I_ + H_)   // 3072
#define N1 (4 * H_)    // 8192

typedef short v8s __attribute__((ext_vector_type(8)));
typedef float v4f __attribute__((ext_vector_type(4)));

__device__ __forceinline__ ushort f2bf(float f) {
    unsigned u = __float_as_uint(f);
    u += 0x7fffu + ((u >> 16) & 1u);   // RNE
    return (ushort)(u >> 16);
}
__device__ __forceinline__ float sigm(float x) { return 1.f / (1.f + __expf(-x)); }
__device__ __forceinline__ float tanh_f(float x) {
    x = fminf(15.f, fmaxf(-15.f, x));
    float e = __expf(2.f * x);
    return (e - 1.f) / (e + 1.f);
}
__device__ __forceinline__ void gload16(const void* g, void* l) {
    __builtin_amdgcn_global_load_lds(
        (const __attribute__((address_space(1))) void*)g,
        (__attribute__((address_space(3))) void*)l, 16, 0, 0);
}

// ---------------------------------------------------------------- conversion
__global__ __launch_bounds__(384) void convert_w(
    const float* __restrict__ Wxi, const float* __restrict__ Whi,
    const float* __restrict__ Wxf, const float* __restrict__ Whf,
    const float* __restrict__ Wxc, const float* __restrict__ Whc,
    const float* __restrict__ Wxo, const float* __restrict__ Who,
    ushort* __restrict__ Wcat)
{
    const int n = blockIdx.x;          // 0..8191
    const int k = threadIdx.x * 8;     // 0..3064
    const int h = n >> 2, g = n & 3;
    const float* src;
    if (k < I_) {
        const float* W = (g == 0) ? Wxi : (g == 1) ? Wxf : (g == 2) ? Wxc : Wxo;
        src = W + (size_t)h * I_ + k;
    } else {
        const float* W = (g == 0) ? Whi : (g == 1) ? Whf : (g == 2) ? Whc : Who;
        src = W + (size_t)h * H_ + (k - I_);
    }
    float4 a = *(const float4*)src;
    float4 b = *(const float4*)(src + 4);
    *(ushort4*)&Wcat[(size_t)n * K1 + k] =
        make_ushort4(f2bf(a.x), f2bf(a.y), f2bf(a.z), f2bf(a.w));
    *(ushort4*)&Wcat[(size_t)n * K1 + k + 4] =
        make_ushort4(f2bf(b.x), f2bf(b.y), f2bf(b.z), f2bf(b.w));
}

__global__ __launch_bounds__(384) void convert_x(
    const float* __restrict__ x, const float* __restrict__ hs, ushort* __restrict__ Xcat)
{
    const int m = blockIdx.x;
    const int k = threadIdx.x * 8;
    const float* src = (k < I_) ? (x + (size_t)m * I_ + k)
                                : (hs + (size_t)m * H_ + (k - I_));
    float4 a = *(const float4*)src;
    float4 b = *(const float4*)(src + 4);
    *(ushort4*)&Xcat[(size_t)m * K1 + k] =
        make_ushort4(f2bf(a.x), f2bf(a.y), f2bf(a.z), f2bf(a.w));
    *(ushort4*)&Xcat[(size_t)m * K1 + k + 4] =
        make_ushort4(f2bf(b.x), f2bf(b.y), f2bf(b.z), f2bf(b.w));
}

__global__ __launch_bounds__(256) void convert_y(
    const float* __restrict__ Why, ushort* __restrict__ WhyB)
{
    const int n = blockIdx.x;
    const int k = threadIdx.x * 8;
    const float* src = Why + (size_t)n * H_ + k;
    float4 a = *(const float4*)src;
    float4 b = *(const float4*)(src + 4);
    *(ushort4*)&WhyB[(size_t)n * H_ + k] =
        make_ushort4(f2bf(a.x), f2bf(a.y), f2bf(a.z), f2bf(a.w));
    *(ushort4*)&WhyB[(size_t)n * H_ + k + 4] =
        make_ushort4(f2bf(b.x), f2bf(b.y), f2bf(b.z), f2bf(b.w));
}

// ---------------------------------------------------------------------------
// GEMM1: 256x256, BK=64, 8 waves (2Mx4N), 2 dbufs x 4 half-tile slots,
// m201 8-phase schedule. Slots (ushort offs): d.A0 = d*32768, d.A1 = +8192,
// d.B0 = +16384, d.B1 = +24576. Stage map per iteration i (t0=2i, t1=2i+1):
//   P1->d1.A0(t1) P2->d1.A1(t1) P3->d0.B0(t0+2) P4->d0.B1(t0+2)
//   P5->d0.A0(t0+2) P6->d0.A1(t0+2) P7->d1.B0(t1+2) P8->d1.B1(t1+2)
// B-frags read entirely at P1/P5 (frees B slots after P2/P6). vmcnt(4) only
// at P4/P8 (leaves the 2 newest half-tiles in flight). XOR swizzle
// byte ^= ((row&7)<<4) on source + read (verified round-4).
// ---------------------------------------------------------------------------

#define STAGE1(SRCBASE, TT, SLOT) {                                          \
    const size_t ko_ = (size_t)(TT) * 64;                                    \
    gload16((SRCBASE) + ko_, (ushort*)lds + (SLOT) + tid * 8);               \
    gload16((SRCBASE) + (size_t)64 * K1 + ko_,                               \
            (ushort*)lds + (SLOT) + 4096 + tid * 8);                         \
}

#define PHASE(DBOFF, MI0, READB, DOSTG, SPTR, STT, SLOT, VMN) {              \
    const ushort* db_ = (const ushort*)lds + (DBOFF);                        \
    if (READB) {                                                             \
        _Pragma("unroll")                                                    \
        for (int ni = 0; ni < 4; ++ni) {                                     \
            bfr[ni][0] = *(const v8s*)&db_[bBaseU + ni * 1024 + cbU0];       \
            bfr[ni][1] = *(const v8s*)&db_[bBaseU + ni * 1024 + cbU1];       \
        }                                                                    \
    }                                                                        \
    v8s a00 = *(const v8s*)&db_[aBaseU + (MI0) * 1024 + cbU0];               \
    v8s a01 = *(const v8s*)&db_[aBaseU + (MI0) * 1024 + cbU1];               \
    v8s a10 = *(const v8s*)&db_[aBaseU + ((MI0) + 1) * 1024 + cbU0];         \
    v8s a11 = *(const v8s*)&db_[aBaseU + ((MI0) + 1) * 1024 + cbU1];         \
    if (DOSTG) { STAGE1(SPTR, STT, SLOT) }                                   \
    __builtin_amdgcn_sched_barrier(0);                                       \
    if ((VMN) == 4) asm volatile("s_waitcnt vmcnt(4)" ::: "memory");         \
    if ((VMN) == 0) asm volatile("s_waitcnt vmcnt(0)" ::: "memory");         \
    __builtin_amdgcn_s_barrier();                                            \
    asm volatile("s_waitcnt lgkmcnt(0)" ::: "memory");                       \
    __builtin_amdgcn_sched_barrier(0);                                       \
    __builtin_amdgcn_s_setprio(1);                                           \
    _Pragma("unroll")                                                        \
    for (int ni = 0; ni < 4; ++ni) {                                         \
        acc[(MI0)][ni]     = __builtin_amdgcn_mfma_f32_16x16x32_bf16(a00, bfr[ni][0], acc[(MI0)][ni], 0, 0, 0);     \
        acc[(MI0)][ni]     = __builtin_amdgcn_mfma_f32_16x16x32_bf16(a01, bfr[ni][1], acc[(MI0)][ni], 0, 0, 0);     \
        acc[(MI0) + 1][ni] = __builtin_amdgcn_mfma_f32_16x16x32_bf16(a10, bfr[ni][0], acc[(MI0) + 1][ni], 0, 0, 0); \
        acc[(MI0) + 1][ni] = __builtin_amdgcn_mfma_f32_16x16x32_bf16(a11, bfr[ni][1], acc[(MI0) + 1][ni], 0, 0, 0); \
    }                                                                        \
    __builtin_amdgcn_s_setprio(0);                                           \
    __builtin_amdgcn_s_barrier();                                            \
}

__global__ __launch_bounds__(512, 2) void gates_mm_256(
    const ushort* __restrict__ A, const ushort* __restrict__ Bm,
    const float* __restrict__ cs,
    const float* __restrict__ bxi, const float* __restrict__ bxf,
    const float* __restrict__ bxc, const float* __restrict__ bxo,
    float* __restrict__ hid_out, float* __restrict__ cell_out,
    ushort* __restrict__ hidB)
{
    __shared__ ushort lds[65536];   // 128 KB

    const int tid  = threadIdx.x;
    const int lane = tid & 63;
    const int w    = tid >> 6;
    const int wm   = w >> 2;            // M half
    const int wn   = w & 3;             // N quarter

    const int nwg = gridDim.x;
    const int xid = (blockIdx.x & 7) * (nwg >> 3) + (blockIdx.x >> 3);
    const int blkM = xid & 15;
    const int blkN = xid >> 4;

    // staging: dest linear (base + tid*16B), source pre-swizzled
    const int srow0 = tid >> 3;                                  // 0..63
    const int scolU = ((((tid & 7) * 16) ^ ((srow0 & 7) << 4)) >> 1);
    const ushort* aH0 = A  + (size_t)(blkM * 256 + srow0) * K1 + scolU;
    const ushort* aH1 = aH0 + (size_t)128 * K1;
    const ushort* bH0 = Bm + (size_t)(blkN * 256 + srow0) * K1 + scolU;
    const ushort* bH1 = bH0 + (size_t)128 * K1;

    // fragment reads: same XOR on full byte address
    const int l15 = lane & 15, l4 = lane >> 4;
    const int flip = (l15 & 7) << 4;
    const int cbU0 = (((l4 * 16))      ^ flip) >> 1;
    const int cbU1 = (((l4 * 16) + 64) ^ flip) >> 1;
    const int aBaseU = wm * 8192 + l15 * 64;
    const int bBaseU = 16384 + (wn >> 1) * 8192 + (wn & 1) * 4096 + l15 * 64;

    v4f acc[8][4];
    #pragma unroll
    for (int mi = 0; mi < 8; ++mi)
      #pragma unroll
      for (int ni = 0; ni < 4; ++ni) acc[mi][ni] = (v4f)0.f;
    v8s bfr[4][2];

    // prologue: d0 full (t=0) + d1.B (t=1); d1.A staged at iter0 P1/P2
    STAGE1(aH0, 0, 0)
    STAGE1(aH1, 0, 8192)
    STAGE1(bH0, 0, 16384)
    STAGE1(bH1, 0, 24576)
    STAGE1(bH0, 1, 32768 + 16384)
    STAGE1(bH1, 1, 32768 + 24576)
    asm volatile("s_waitcnt vmcnt(4)" ::: "memory");   // d0 complete
    __builtin_amdgcn_s_barrier();

    #pragma unroll 1
    for (int i = 0; i < 23; ++i) {
        const int t1 = 2 * i + 1, tn = 2 * i + 2, tn1 = 2 * i + 3;
        PHASE(0,     0, 1, 1, aH0, t1,  32768 + 0,     -1)
        PHASE(0,     2, 0, 1, aH1, t1,  32768 + 8192,  -1)
        PHASE(0,     4, 0, 1, bH0, tn,  16384,         -1)
        PHASE(0,     6, 0, 1, bH1, tn,  24576,          4)
        PHASE(32768, 0, 1, 1, aH0, tn,  0,             -1)
        PHASE(32768, 2, 0, 1, aH1, tn,  8192,          -1)
        PHASE(32768, 4, 0, 1, bH0, tn1, 32768 + 16384, -1)
        PHASE(32768, 6, 0, 1, bH1, tn1, 32768 + 24576,  4)
    }
    // peeled last iteration (t0=46, t1=47): only d1.A(47) still to stage
    PHASE(0,     0, 1, 1, aH0, 47, 32768 + 0,    -1)
    PHASE(0,     2, 0, 1, aH1, 47, 32768 + 8192, -1)
    PHASE(0,     4, 0, 0, aH0, 0, 0,             -1)
    PHASE(0,     6, 0, 0, aH0, 0, 0,              0)
    PHASE(32768, 0, 1, 0, aH0, 0, 0,             -1)
    PHASE(32768, 2, 0, 0, aH0, 0, 0,             -1)
    PHASE(32768, 4, 0, 0, aH0, 0, 0,             -1)
    PHASE(32768, 6, 0, 0, aH0, 0, 0,             -1)

    // =========================== fused LSTM epilogue ===========================
    float*  csT = (float*)lds;                     // [128][64] f32
    float*  cT  = (float*)lds + 8192;
    float*  hT  = (float*)lds + 16384;
    ushort* hbT = (ushort*)((float*)lds + 24576);  // [128][64] bf16

    const int g = lane & 3;
    const int q = lane & 60;
    int hj[4], hl[4]; float biasj[4];
    #pragma unroll
    for (int ni = 0; ni < 4; ++ni) {
        const int nn = blkN * 256 + wn * 64 + ni * 16 + l15;
        hj[ni] = nn >> 2;
        hl[ni] = (wn * 64 + ni * 16 + l15) >> 2;
        const float* bp = (g == 0) ? bxi : (g == 1) ? bxf : (g == 2) ? bxc : bxo;
        biasj[ni] = bp[hj[ni]];
    }
    const int Mbase = blkM * 256;
    const int Hg0   = blkN * 64;
    const int erow  = tid >> 2;
    const int ecol  = (tid & 3) * 16;

    #pragma unroll 1
    for (int mh = 0; mh < 2; ++mh) {
        __syncthreads();
        {
            const float* src = cs + (size_t)(Mbase + mh * 128 + erow) * H_ + Hg0 + ecol;
            #pragma unroll
            for (int qq = 0; qq < 4; ++qq)
                *(float4*)&csT[erow * 64 + ecol + qq * 4] = *(const float4*)(src + qq * 4);
        }
        __syncthreads();
        if (wm == mh) {
            #pragma unroll
            for (int mi = 0; mi < 8; ++mi) {
              #pragma unroll
              for (int r = 0; r < 4; ++r) {
                const int ml = mi * 16 + l4 * 4 + r;
                #pragma unroll
                for (int ni = 0; ni < 4; ++ni) {
                    const float v = acc[mi][ni][r] + biasj[ni];
                    const float gi = __shfl(v, q + 0, 64);
                    const float gf = __shfl(v, q + 1, 64);
                    const float gc = __shfl(v, q + 2, 64);
                    const float go = __shfl(v, q + 3, 64);
                    const float Ig = sigm(gi), Fg = sigm(gf);
                    const float Cg = tanh_f(gc), Og = sigm(go);
                    const float c_old = csT[ml * 64 + hl[ni]];
                    const float c_new = Fg * c_old + Ig * Cg;
                    const float h_new = Og * tanh_f(c_new);
                    if (g == 0)      cT [ml * 64 + hl[ni]] = c_new;
                    else if (g == 1) hT [ml * 64 + hl[ni]] = h_new;
                    else if (g == 2) hbT[ml * 64 + hl[ni]] = f2bf(h_new);
                }
              }
            }
        }
        __syncthreads();
        {
            const size_t gof = (size_t)(Mbase + mh * 128 + erow) * H_ + Hg0 + ecol;
            #pragma unroll
            for (int qq = 0; qq < 4; ++qq) {
                *(float4*)&cell_out[gof + qq * 4] = *(const float4*)&cT[erow * 64 + ecol + qq * 4];
                *(float4*)&hid_out [gof + qq * 4] = *(const float4*)&hT[erow * 64 + ecol + qq * 4];
            }
            *(uint4*)&hidB[gof]     = *(const uint4*)&hbT[erow * 64 + ecol];
            *(uint4*)&hidB[gof + 8] = *(const uint4*)&hbT[erow * 64 + ecol + 8];
        }
    }
}

// ---------------------------------------------------------------------------
// GEMM2: out = hidB @ WhyB^T + b   (128x128 m97-style)
// ---------------------------------------------------------------------------
__global__ __launch_bounds__(256) void out_mm_bf16(
    const ushort* __restrict__ A, const ushort* __restrict__ Bm,
    const float* __restrict__ bw, float* __restrict__ out)
{
    __shared__ ushort As[128 * 32];
    __shared__ ushort Bs[128 * 32];
    const int tid  = threadIdx.x;
    const int lane = tid & 63;
    const int w    = tid >> 6;
    const int wm = w >> 1, wn = w & 1;
    const int blkN = blockIdx.x, blkM = blockIdx.y;
    const int srow = w * 16 + (lane >> 2);
    const int scol = (lane & 3) * 8;

    v4f acc[4][4];
    #pragma unroll
    for (int i = 0; i < 4; ++i)
      #pragma unroll
      for (int j = 0; j < 4; ++j) acc[i][j] = (v4f)0.f;

    for (int k0 = 0; k0 < H_; k0 += 32) {
        #pragma unroll
        for (int it = 0; it < 2; ++it) {
            const int row = it * 64 + srow;
            gload16(A  + (size_t)(blkM * 128 + row) * H_ + k0 + scol,
                    &As[w * 512 + it * 2048]);
            gload16(Bm + (size_t)(blkN * 128 + row) * H_ + k0 + scol,
                    &Bs[w * 512 + it * 2048]);
        }
        __syncthreads();
        v8s afr[4], bfr[4];
        #pragma unroll
        for (int i = 0; i < 4; ++i)
            afr[i] = *(const v8s*)&As[(wm * 64 + i * 16 + (lane & 15)) * 32 + (lane >> 4) * 8];
        #pragma unroll
        for (int j = 0; j < 4; ++j)
            bfr[j] = *(const v8s*)&Bs[(wn * 64 + j * 16 + (lane & 15)) * 32 + (lane >> 4) * 8];
        #pragma unroll
        for (int i = 0; i < 4; ++i)
          #pragma unroll
          for (int j = 0; j < 4; ++j)
            acc[i][j] = __builtin_amdgcn_mfma_f32_16x16x32_bf16(afr[i], bfr[j], acc[i][j], 0, 0, 0);
        __syncthreads();
    }
    #pragma unroll
    for (int i = 0; i < 4; ++i) {
      #pragma unroll
      for (int r = 0; r < 4; ++r) {
        const int m = blkM * 128 + wm * 64 + i * 16 + (lane >> 4) * 4 + r;
        #pragma unroll
        for (int j = 0; j < 4; ++j) {
            const int n = blkN * 128 + wn * 64 + j * 16 + (lane & 15);
            out[(size_t)m * O_ + n] = acc[i][j][r] + bw[n];
        }
      }
    }
}

extern "C" void kernel_launch(void* const* d_in, const int* in_sizes, int n_in,
                              void* d_out, int out_size, void* d_ws, size_t ws_size,
                              hipStream_t stream) {
    const float* x   = (const float*)d_in[0];
    const float* hs  = (const float*)d_in[1];
    const float* cs  = (const float*)d_in[2];
    const float* Wxi = (const float*)d_in[3];
    const float* bxi = (const float*)d_in[4];
    const float* Whi = (const float*)d_in[5];
    const float* Wxf = (const float*)d_in[6];
    const float* bxf = (const float*)d_in[7];
    const float* Whf = (const float*)d_in[8];
    const float* Wxc = (const float*)d_in[9];
    const float* bxc = (const float*)d_in[10];
    const float* Whc = (const float*)d_in[11];
    const float* Wxo = (const float*)d_in[12];
    const float* bxo = (const float*)d_in[13];
    const float* Who = (const float*)d_in[14];
    const float* Why = (const float*)d_in[15];
    const float* bwy = (const float*)d_in[16];

    float* out      = (float*)d_out;
    float* hid_out  = out + (size_t)B_ * O_;
    float* cell_out = hid_out + (size_t)B_ * H_;

    const size_t szW = (size_t)N1 * K1;
    const size_t szX = (size_t)B_ * K1;
    const size_t szY = (size_t)O_ * H_;

    ushort* Wcat = (ushort*)d_ws;
    ushort* Xcat = Wcat + szW;
    ushort* WhyB = Xcat + szX;
    ushort* HidB = WhyB + szY;

    convert_w<<<dim3(N1), 384, 0, stream>>>(Wxi, Whi, Wxf, Whf, Wxc, Whc, Wxo, Who, Wcat);
    convert_x<<<dim3(B_), 384, 0, stream>>>(x, hs, Xcat);
    convert_y<<<dim3(O_), 256, 0, stream>>>(Why, WhyB);

    gates_mm_256<<<dim3((N1 / 256) * (B_ / 256)), 512, 0, stream>>>(
        Xcat, Wcat, cs, bxi, bxf, bxc, bxo, hid_out, cell_out, HidB);
    out_mm_bf16<<<dim3(O_ / 128, B_ / 128), 256, 0, stream>>>(
        HidB, WhyB, bwy, out);
}

// Round 7
// 399.697 us; speedup vs baseline: 1.2671x; 1.2671x over previous
//
#include <hip/hip_runtime.h>
#include <hip/hip_bf16.h>

#define B_ 4096
#define I_ 1024
#define H_ 2048
#define O_ 1024
#define K1 (I_ + H_)   // 3072
#define N1 (4 * H_)    // 8192

typedef short v8s __attribute__((ext_vector_type(8)));
typedef float v4f __attribute__((ext_vector_type(4)));

__device__ __forceinline__ ushort f2bf(float f) {
    unsigned u = __float_as_uint(f);
    u += 0x7fffu + ((u >> 16) & 1u);   // RNE
    return (ushort)(u >> 16);
}
__device__ __forceinline__ float sigm(float x) { return 1.f / (1.f + __expf(-x)); }
__device__ __forceinline__ float tanh_f(float x) {
    x = fminf(15.f, fmaxf(-15.f, x));
    float e = __expf(2.f * x);
    return (e - 1.f) / (e + 1.f);
}
__device__ __forceinline__ void gload16(const void* g, void* l) {
    __builtin_amdgcn_global_load_lds(
        (const __attribute__((address_space(1))) void*)g,
        (__attribute__((address_space(3))) void*)l, 16, 0, 0);
}

// ---------------------------------------------------------------- conversion
__global__ __launch_bounds__(384) void convert_w(
    const float* __restrict__ Wxi, const float* __restrict__ Whi,
    const float* __restrict__ Wxf, const float* __restrict__ Whf,
    const float* __restrict__ Wxc, const float* __restrict__ Whc,
    const float* __restrict__ Wxo, const float* __restrict__ Who,
    ushort* __restrict__ Wcat)
{
    const int n = blockIdx.x;          // 0..8191
    const int k = threadIdx.x * 8;     // 0..3064
    const int h = n >> 2, g = n & 3;
    const float* src;
    if (k < I_) {
        const float* W = (g == 0) ? Wxi : (g == 1) ? Wxf : (g == 2) ? Wxc : Wxo;
        src = W + (size_t)h * I_ + k;
    } else {
        const float* W = (g == 0) ? Whi : (g == 1) ? Whf : (g == 2) ? Whc : Who;
        src = W + (size_t)h * H_ + (k - I_);
    }
    float4 a = *(const float4*)src;
    float4 b = *(const float4*)(src + 4);
    *(ushort4*)&Wcat[(size_t)n * K1 + k] =
        make_ushort4(f2bf(a.x), f2bf(a.y), f2bf(a.z), f2bf(a.w));
    *(ushort4*)&Wcat[(size_t)n * K1 + k + 4] =
        make_ushort4(f2bf(b.x), f2bf(b.y), f2bf(b.z), f2bf(b.w));
}

__global__ __launch_bounds__(384) void convert_x(
    const float* __restrict__ x, const float* __restrict__ hs, ushort* __restrict__ Xcat)
{
    const int m = blockIdx.x;
    const int k = threadIdx.x * 8;
    const float* src = (k < I_) ? (x + (size_t)m * I_ + k)
                                : (hs + (size_t)m * H_ + (k - I_));
    float4 a = *(const float4*)src;
    float4 b = *(const float4*)(src + 4);
    *(ushort4*)&Xcat[(size_t)m * K1 + k] =
        make_ushort4(f2bf(a.x), f2bf(a.y), f2bf(a.z), f2bf(a.w));
    *(ushort4*)&Xcat[(size_t)m * K1 + k + 4] =
        make_ushort4(f2bf(b.x), f2bf(b.y), f2bf(b.z), f2bf(b.w));
}

__global__ __launch_bounds__(256) void convert_y(
    const float* __restrict__ Why, ushort* __restrict__ WhyB)
{
    const int n = blockIdx.x;
    const int k = threadIdx.x * 8;
    const float* src = Why + (size_t)n * H_ + k;
    float4 a = *(const float4*)src;
    float4 b = *(const float4*)(src + 4);
    *(ushort4*)&WhyB[(size_t)n * H_ + k] =
        make_ushort4(f2bf(a.x), f2bf(a.y), f2bf(a.z), f2bf(a.w));
    *(ushort4*)&WhyB[(size_t)n * H_ + k + 4] =
        make_ushort4(f2bf(b.x), f2bf(b.y), f2bf(b.z), f2bf(b.w));
}

// ---------------------------------------------------------------------------
// GEMM1: 128x128 tile, BK=64, 4 waves (2x2), DOUBLE-buffered 64KB LDS ->
// 2 blocks/CU co-resident (TLP hides sync stalls, m114 mechanism).
// Counted vmcnt(8); 2 raw barriers per K-64. Swizzle: LDS rows are 128B
// (64 bf16); 16B slot s of row r holds logical slot s^(r&7); both sides.
// Epilogue: LDS-staged coalesced cs read + cell/hid/hidB writes.
// ---------------------------------------------------------------------------

#define STAGE(D, TT) {                                                        \
    const int kb_ = (TT) * 64;                                                \
    ushort* l0_ = (ushort*)lds + (D) * 16384 + tid * 8;                       \
    gload16(aSrc + kb_,                 l0_);                                 \
    gload16(aSrc + 32 * K1 + kb_,       l0_ + 2048);                          \
    gload16(aSrc + 64 * K1 + kb_,       l0_ + 4096);                          \
    gload16(aSrc + 96 * K1 + kb_,       l0_ + 6144);                          \
    gload16(bSrc + kb_,                 l0_ + 8192);                          \
    gload16(bSrc + 32 * K1 + kb_,       l0_ + 10240);                         \
    gload16(bSrc + 64 * K1 + kb_,       l0_ + 12288);                         \
    gload16(bSrc + 96 * K1 + kb_,       l0_ + 14336);                         \
}

#define COMPUTE(D) {                                                          \
    const ushort* ba_ = (const ushort*)lds + (D) * 16384 + aRowU;             \
    const ushort* bb_ = (const ushort*)lds + (D) * 16384 + 8192 + bRowU;      \
    v8s af_[4][2], bf_[4][2];                                                 \
    _Pragma("unroll")                                                         \
    for (int mi = 0; mi < 4; ++mi) {                                          \
        af_[mi][0] = *(const v8s*)&ba_[mi * 1024 + col0];                     \
        af_[mi][1] = *(const v8s*)&ba_[mi * 1024 + col1];                     \
    }                                                                         \
    _Pragma("unroll")                                                         \
    for (int ni = 0; ni < 4; ++ni) {                                          \
        bf_[ni][0] = *(const v8s*)&bb_[ni * 1024 + col0];                     \
        bf_[ni][1] = *(const v8s*)&bb_[ni * 1024 + col1];                     \
    }                                                                         \
    _Pragma("unroll")                                                         \
    for (int mi = 0; mi < 4; ++mi)                                            \
      _Pragma("unroll")                                                       \
      for (int ni = 0; ni < 4; ++ni) {                                        \
        acc[mi][ni] = __builtin_amdgcn_mfma_f32_16x16x32_bf16(                \
            af_[mi][0], bf_[ni][0], acc[mi][ni], 0, 0, 0);                    \
        acc[mi][ni] = __builtin_amdgcn_mfma_f32_16x16x32_bf16(                \
            af_[mi][1], bf_[ni][1], acc[mi][ni], 0, 0, 0);                    \
      }                                                                       \
}

__global__ __launch_bounds__(256, 2) void gates_mm_128(
    const ushort* __restrict__ A, const ushort* __restrict__ Bm,
    const float* __restrict__ cs,
    const float* __restrict__ bxi, const float* __restrict__ bxf,
    const float* __restrict__ bxc, const float* __restrict__ bxo,
    float* __restrict__ hid_out, float* __restrict__ cell_out,
    ushort* __restrict__ hidB)
{
    __shared__ ushort lds[32768];   // 64 KB: buf d at d*16384 (A 8192 | B 8192)

    const int tid  = threadIdx.x;
    const int lane = tid & 63;
    const int w    = tid >> 6;
    const int wm = w >> 1, wn = w & 1;

    // XCD swizzle, consecutive xid share blkN (B-panel L2 reuse); 2048%8==0
    const int xid = ((int)blockIdx.x & 7) * 256 + ((int)blockIdx.x >> 3);
    const int blkM = xid & 31;          // 32 M-blocks
    const int blkN = xid >> 5;          // 64 N-blocks

    // staging: source pre-swizzled (slot s of row r <- logical slot s^(r&7))
    const int srowS = tid >> 3;         // 0..31
    const int colES = (((tid & 7) ^ (srowS & 7)) << 3);
    const ushort* aSrc = A  + (size_t)(blkM * 128 + srowS) * K1 + colES;
    const ushort* bSrc = Bm + (size_t)(blkN * 128 + srowS) * K1 + colES;

    // fragment reads: row = (wm|wn)*64 + mi*16 + l15, slot = (4c+l4)^(l15&7)
    const int l15 = lane & 15, l4 = lane >> 4;
    const int fx = l15 & 7;
    const int col0 = ((l4      ^ fx) << 3);
    const int col1 = (((4 + l4) ^ fx) << 3);
    const int aRowU = (wm * 64 + l15) * 64;
    const int bRowU = (wn * 64 + l15) * 64;

    v4f acc[4][4];
    #pragma unroll
    for (int mi = 0; mi < 4; ++mi)
      #pragma unroll
      for (int ni = 0; ni < 4; ++ni) acc[mi][ni] = (v4f)0.f;

    STAGE(0, 0)
    #pragma unroll 1
    for (int t = 0; t < 47; ++t) {
        STAGE((t + 1) & 1, t + 1)
        asm volatile("s_waitcnt vmcnt(8)" ::: "memory");
        __builtin_amdgcn_s_barrier();
        COMPUTE(t & 1)
        __builtin_amdgcn_s_barrier();
    }
    asm volatile("s_waitcnt vmcnt(0)" ::: "memory");
    __builtin_amdgcn_s_barrier();
    COMPUTE(1)
    __builtin_amdgcn_s_barrier();

    // ======================= fused LSTM epilogue (LDS-staged) ================
    float*  csT = (float*)lds;                      // [128][32] f32  (16KB)
    float*  cT  = (float*)lds + 4096;               // 16KB
    float*  hT  = (float*)lds + 8192;               // 16KB
    ushort* hbT = (ushort*)((float*)lds + 12288);   // [128][32] bf16 (8KB)

    const int g = lane & 3;
    const int q = lane & 60;
    const int Mb = blkM * 128;
    const int hbase = blkN * 32;

    int hl[4]; float biasj[4];
    #pragma unroll
    for (int ni = 0; ni < 4; ++ni) {
        hl[ni] = wn * 16 + ni * 4 + (l15 >> 2);     // 0..31
        const float* bp = (g == 0) ? bxi : (g == 1) ? bxf : (g == 2) ? bxc : bxo;
        biasj[ni] = bp[hbase + hl[ni]];
    }

    const int erow = tid >> 1;           // 0..127
    const int ecolf = (tid & 1) * 16;    // f32 col
    // coop-load cs tile [128][32]
    {
        const float* src = cs + (size_t)(Mb + erow) * H_ + hbase + ecolf;
        #pragma unroll
        for (int qq = 0; qq < 4; ++qq)
            *(float4*)&csT[erow * 32 + ecolf + qq * 4] = *(const float4*)(src + qq * 4);
    }
    __syncthreads();
    #pragma unroll
    for (int mi = 0; mi < 4; ++mi) {
      #pragma unroll
      for (int r = 0; r < 4; ++r) {
        const int ml = wm * 64 + mi * 16 + l4 * 4 + r;   // 0..127
        #pragma unroll
        for (int ni = 0; ni < 4; ++ni) {
            const float v = acc[mi][ni][r] + biasj[ni];
            const float gi = __shfl(v, q + 0, 64);
            const float gf = __shfl(v, q + 1, 64);
            const float gc = __shfl(v, q + 2, 64);
            const float go = __shfl(v, q + 3, 64);
            const float Ig = sigm(gi), Fg = sigm(gf);
            const float Cg = tanh_f(gc), Og = sigm(go);
            const float c_old = csT[ml * 32 + hl[ni]];
            const float c_new = Fg * c_old + Ig * Cg;
            const float h_new = Og * tanh_f(c_new);
            if (g == 0)      cT [ml * 32 + hl[ni]] = c_new;
            else if (g == 1) hT [ml * 32 + hl[ni]] = h_new;
            else if (g == 2) hbT[ml * 32 + hl[ni]] = f2bf(h_new);
        }
      }
    }
    __syncthreads();
    // coop-store coalesced
    {
        const size_t gof = (size_t)(Mb + erow) * H_ + hbase + ecolf;
        #pragma unroll
        for (int qq = 0; qq < 4; ++qq) {
            *(float4*)&cell_out[gof + qq * 4] = *(const float4*)&cT[erow * 32 + ecolf + qq * 4];
            *(float4*)&hid_out [gof + qq * 4] = *(const float4*)&hT[erow * 32 + ecolf + qq * 4];
        }
        *(uint4*)&hidB[gof]     = *(const uint4*)&hbT[erow * 32 + ecolf];
        *(uint4*)&hidB[gof + 8] = *(const uint4*)&hbT[erow * 32 + ecolf + 8];
    }
}

// ---------------------------------------------------------------------------
// GEMM2: out = hidB @ WhyB^T + b   (128x128 m97-style)
// ---------------------------------------------------------------------------
__global__ __launch_bounds__(256) void out_mm_bf16(
    const ushort* __restrict__ A, const ushort* __restrict__ Bm,
    const float* __restrict__ bw, float* __restrict__ out)
{
    __shared__ ushort As[128 * 32];
    __shared__ ushort Bs[128 * 32];
    const int tid  = threadIdx.x;
    const int lane = tid & 63;
    const int w    = tid >> 6;
    const int wm = w >> 1, wn = w & 1;
    const int blkN = blockIdx.x, blkM = blockIdx.y;
    const int srow = w * 16 + (lane >> 2);
    const int scol = (lane & 3) * 8;

    v4f acc[4][4];
    #pragma unroll
    for (int i = 0; i < 4; ++i)
      #pragma unroll
      for (int j = 0; j < 4; ++j) acc[i][j] = (v4f)0.f;

    for (int k0 = 0; k0 < H_; k0 += 32) {
        #pragma unroll
        for (int it = 0; it < 2; ++it) {
            const int row = it * 64 + srow;
            gload16(A  + (size_t)(blkM * 128 + row) * H_ + k0 + scol,
                    &As[w * 512 + it * 2048]);
            gload16(Bm + (size_t)(blkN * 128 + row) * H_ + k0 + scol,
                    &Bs[w * 512 + it * 2048]);
        }
        __syncthreads();
        v8s afr[4], bfr[4];
        #pragma unroll
        for (int i = 0; i < 4; ++i)
            afr[i] = *(const v8s*)&As[(wm * 64 + i * 16 + (lane & 15)) * 32 + (lane >> 4) * 8];
        #pragma unroll
        for (int j = 0; j < 4; ++j)
            bfr[j] = *(const v8s*)&Bs[(wn * 64 + j * 16 + (lane & 15)) * 32 + (lane >> 4) * 8];
        #pragma unroll
        for (int i = 0; i < 4; ++i)
          #pragma unroll
          for (int j = 0; j < 4; ++j)
            acc[i][j] = __builtin_amdgcn_mfma_f32_16x16x32_bf16(afr[i], bfr[j], acc[i][j], 0, 0, 0);
        __syncthreads();
    }
    #pragma unroll
    for (int i = 0; i < 4; ++i) {
      #pragma unroll
      for (int r = 0; r < 4; ++r) {
        const int m = blkM * 128 + wm * 64 + i * 16 + (lane >> 4) * 4 + r;
        #pragma unroll
        for (int j = 0; j < 4; ++j) {
            const int n = blkN * 128 + wn * 64 + j * 16 + (lane & 15);
            out[(size_t)m * O_ + n] = acc[i][j][r] + bw[n];
        }
      }
    }
}

extern "C" void kernel_launch(void* const* d_in, const int* in_sizes, int n_in,
                              void* d_out, int out_size, void* d_ws, size_t ws_size,
                              hipStream_t stream) {
    const float* x   = (const float*)d_in[0];
    const float* hs  = (const float*)d_in[1];
    const float* cs  = (const float*)d_in[2];
    const float* Wxi = (const float*)d_in[3];
    const float* bxi = (const float*)d_in[4];
    const float* Whi = (const float*)d_in[5];
    const float* Wxf = (const float*)d_in[6];
    const float* bxf = (const float*)d_in[7];
    const float* Whf = (const float*)d_in[8];
    const float* Wxc = (const float*)d_in[9];
    const float* bxc = (const float*)d_in[10];
    const float* Whc = (const float*)d_in[11];
    const float* Wxo = (const float*)d_in[12];
    const float* bxo = (const float*)d_in[13];
    const float* Who = (const float*)d_in[14];
    const float* Why = (const float*)d_in[15];
    const float* bwy = (const float*)d_in[16];

    float* out      = (float*)d_out;
    float* hid_out  = out + (size_t)B_ * O_;
    float* cell_out = hid_out + (size_t)B_ * H_;

    const size_t szW = (size_t)N1 * K1;
    const size_t szX = (size_t)B_ * K1;
    const size_t szY = (size_t)O_ * H_;

    ushort* Wcat = (ushort*)d_ws;
    ushort* Xcat = Wcat + szW;
    ushort* WhyB = Xcat + szX;
    ushort* HidB = WhyB + szY;

    convert_w<<<dim3(N1), 384, 0, stream>>>(Wxi, Whi, Wxf, Whf, Wxc, Whc, Wxo, Who, Wcat);
    convert_x<<<dim3(B_), 384, 0, stream>>>(x, hs, Xcat);
    convert_y<<<dim3(O_), 256, 0, stream>>>(Why, WhyB);

    gates_mm_128<<<dim3((N1 / 128) * (B_ / 128)), 256, 0, stream>>>(
        Xcat, Wcat, cs, bxi, bxf, bxc, bxo, hid_out, cell_out, HidB);
    out_mm_bf16<<<dim3(O_ / 128, B_ / 128), 256, 0, stream>>>(
        HidB, WhyB, bwy, out);
}

// Round 10
// 367.960 us; speedup vs baseline: 1.3764x; 1.0862x over previous
//
#include <hip/hip_runtime.h>
#include <hip/hip_bf16.h>

#define B_ 4096
#define I_ 1024
#define H_ 2048
#define O_ 1024
#define K1 (I_ + H_)   // 3072
#define N1 (4 * H_)    // 8192

typedef short v8s __attribute__((ext_vector_type(8)));
typedef float v4f __attribute__((ext_vector_type(4)));

__device__ __forceinline__ ushort f2bf(float f) {
    unsigned u = __float_as_uint(f);
    u += 0x7fffu + ((u >> 16) & 1u);   // RNE
    return (ushort)(u >> 16);
}
__device__ __forceinline__ float sigm(float x) { return 1.f / (1.f + __expf(-x)); }
__device__ __forceinline__ float tanh_f(float x) {
    x = fminf(15.f, fmaxf(-15.f, x));
    float e = __expf(2.f * x);
    return (e - 1.f) / (e + 1.f);
}
__device__ __forceinline__ void gload16(const void* g, void* l) {
    __builtin_amdgcn_global_load_lds(
        (const __attribute__((address_space(1))) void*)g,
        (__attribute__((address_space(3))) void*)l, 16, 0, 0);
}
// full barrier with compiler reorder fence (raw s_barrier has NO IR/sched
// memory semantics: loads/stores CAN be moved across it -> replay races)
__device__ __forceinline__ void barrier_fenced() {
    __builtin_amdgcn_sched_barrier(0);
    asm volatile("" ::: "memory");
    __builtin_amdgcn_s_barrier();
    __builtin_amdgcn_sched_barrier(0);
    asm volatile("" ::: "memory");
}

// ---------------------------------------------------------------- conversion
__global__ __launch_bounds__(384) void convert_w(
    const float* __restrict__ Wxi, const float* __restrict__ Whi,
    const float* __restrict__ Wxf, const float* __restrict__ Whf,
    const float* __restrict__ Wxc, const float* __restrict__ Whc,
    const float* __restrict__ Wxo, const float* __restrict__ Who,
    ushort* __restrict__ Wcat)
{
    const int n = blockIdx.x;          // 0..8191
    const int k = threadIdx.x * 8;     // 0..3064
    const int h = n >> 2, g = n & 3;
    const float* src;
    if (k < I_) {
        const float* W = (g == 0) ? Wxi : (g == 1) ? Wxf : (g == 2) ? Wxc : Wxo;
        src = W + (size_t)h * I_ + k;
    } else {
        const float* W = (g == 0) ? Whi : (g == 1) ? Whf : (g == 2) ? Whc : Who;
        src = W + (size_t)h * H_ + (k - I_);
    }
    float4 a = *(const float4*)src;
    float4 b = *(const float4*)(src + 4);
    *(ushort4*)&Wcat[(size_t)n * K1 + k] =
        make_ushort4(f2bf(a.x), f2bf(a.y), f2bf(a.z), f2bf(a.w));
    *(ushort4*)&Wcat[(size_t)n * K1 + k + 4] =
        make_ushort4(f2bf(b.x), f2bf(b.y), f2bf(b.z), f2bf(b.w));
}

__global__ __launch_bounds__(384) void convert_x(
    const float* __restrict__ x, const float* __restrict__ hs, ushort* __restrict__ Xcat)
{
    const int m = blockIdx.x;
    const int k = threadIdx.x * 8;
    const float* src = (k < I_) ? (x + (size_t)m * I_ + k)
                                : (hs + (size_t)m * H_ + (k - I_));
    float4 a = *(const float4*)src;
    float4 b = *(const float4*)(src + 4);
    *(ushort4*)&Xcat[(size_t)m * K1 + k] =
        make_ushort4(f2bf(a.x), f2bf(a.y), f2bf(a.z), f2bf(a.w));
    *(ushort4*)&Xcat[(size_t)m * K1 + k + 4] =
        make_ushort4(f2bf(b.x), f2bf(b.y), f2bf(b.z), f2bf(b.w));
}

__global__ __launch_bounds__(256) void convert_y(
    const float* __restrict__ Why, ushort* __restrict__ WhyB)
{
    const int n = blockIdx.x;
    const int k = threadIdx.x * 8;
    const float* src = Why + (size_t)n * H_ + k;
    float4 a = *(const float4*)src;
    float4 b = *(const float4*)(src + 4);
    *(ushort4*)&WhyB[(size_t)n * H_ + k] =
        make_ushort4(f2bf(a.x), f2bf(a.y), f2bf(a.z), f2bf(a.w));
    *(ushort4*)&WhyB[(size_t)n * H_ + k + 4] =
        make_ushort4(f2bf(b.x), f2bf(b.y), f2bf(b.z), f2bf(b.w));
}

// ---------------------------------------------------------------------------
// GEMM1: 128x128, BK=64, 4 waves, double-buffered 64KB LDS (2 blocks/CU),
// counted vmcnt(8), fenced barriers. blkN-fast 2D dispatch. Epilogue with
// padded LDS strides (36 f32 / 40 ushort).
// ---------------------------------------------------------------------------

#define STAGE(D, TT) {                                                        \
    const int kb_ = (TT) * 64;                                                \
    ushort* l0_ = (ushort*)lds + (D) * 16384 + tid * 8;                       \
    gload16(aSrc + kb_,                 l0_);                                 \
    gload16(aSrc + 32 * K1 + kb_,       l0_ + 2048);                          \
    gload16(aSrc + 64 * K1 + kb_,       l0_ + 4096);                          \
    gload16(aSrc + 96 * K1 + kb_,       l0_ + 6144);                          \
    gload16(bSrc + kb_,                 l0_ + 8192);                          \
    gload16(bSrc + 32 * K1 + kb_,       l0_ + 10240);                         \
    gload16(bSrc + 64 * K1 + kb_,       l0_ + 12288);                         \
    gload16(bSrc + 96 * K1 + kb_,       l0_ + 14336);                         \
}

#define COMPUTE(D) {                                                          \
    const ushort* ba_ = (const ushort*)lds + (D) * 16384 + aRowU;             \
    const ushort* bb_ = (const ushort*)lds + (D) * 16384 + 8192 + bRowU;      \
    v8s af_[4][2], bf_[4][2];                                                 \
    _Pragma("unroll")                                                         \
    for (int mi = 0; mi < 4; ++mi) {                                          \
        af_[mi][0] = *(const v8s*)&ba_[mi * 1024 + col0];                     \
        af_[mi][1] = *(const v8s*)&ba_[mi * 1024 + col1];                     \
    }                                                                         \
    _Pragma("unroll")                                                         \
    for (int ni = 0; ni < 4; ++ni) {                                          \
        bf_[ni][0] = *(const v8s*)&bb_[ni * 1024 + col0];                     \
        bf_[ni][1] = *(const v8s*)&bb_[ni * 1024 + col1];                     \
    }                                                                         \
    _Pragma("unroll")                                                         \
    for (int mi = 0; mi < 4; ++mi)                                            \
      _Pragma("unroll")                                                       \
      for (int ni = 0; ni < 4; ++ni) {                                        \
        acc[mi][ni] = __builtin_amdgcn_mfma_f32_16x16x32_bf16(                \
            af_[mi][0], bf_[ni][0], acc[mi][ni], 0, 0, 0);                    \
        acc[mi][ni] = __builtin_amdgcn_mfma_f32_16x16x32_bf16(                \
            af_[mi][1], bf_[ni][1], acc[mi][ni], 0, 0, 0);                    \
      }                                                                       \
}

__global__ __launch_bounds__(256, 2) void gates_mm_128(
    const ushort* __restrict__ A, const ushort* __restrict__ Bm,
    const float* __restrict__ cs,
    const float* __restrict__ bxi, const float* __restrict__ bxf,
    const float* __restrict__ bxc, const float* __restrict__ bxo,
    float* __restrict__ hid_out, float* __restrict__ cell_out,
    ushort* __restrict__ hidB)
{
    __shared__ ushort lds[32768];   // 64 KB: buf d at d*16384 (A 8192 | B 8192)

    const int tid  = threadIdx.x;
    const int lane = tid & 63;
    const int w    = tid >> 6;
    const int wm = w >> 1, wn = w & 1;

    // blkN-fast mapping (A-panel reuse across consecutive blocks)
    const int blkN = blockIdx.x;        // 0..63
    const int blkM = blockIdx.y;        // 0..31

    // staging: source pre-swizzled (slot s of row r <- logical slot s^(r&7))
    const int srowS = tid >> 3;         // 0..31
    const int colES = (((tid & 7) ^ (srowS & 7)) << 3);
    const ushort* aSrc = A  + (size_t)(blkM * 128 + srowS) * K1 + colES;
    const ushort* bSrc = Bm + (size_t)(blkN * 128 + srowS) * K1 + colES;

    // fragment reads: row = (wm|wn)*64 + mi*16 + l15, slot = (4c+l4)^(l15&7)
    const int l15 = lane & 15, l4 = lane >> 4;
    const int fx = l15 & 7;
    const int col0 = ((l4      ^ fx) << 3);
    const int col1 = (((4 + l4) ^ fx) << 3);
    const int aRowU = (wm * 64 + l15) * 64;
    const int bRowU = (wn * 64 + l15) * 64;

    v4f acc[4][4];
    #pragma unroll
    for (int mi = 0; mi < 4; ++mi)
      #pragma unroll
      for (int ni = 0; ni < 4; ++ni) acc[mi][ni] = (v4f)0.f;

    STAGE(0, 0)
    #pragma unroll 1
    for (int t = 0; t < 47; ++t) {
        STAGE((t + 1) & 1, t + 1)
        asm volatile("s_waitcnt vmcnt(8)" ::: "memory");
        barrier_fenced();                 // readers may enter buf t&1
        COMPUTE(t & 1)
        barrier_fenced();                 // all reads done before next STAGE
    }
    asm volatile("s_waitcnt vmcnt(0)" ::: "memory");
    barrier_fenced();
    COMPUTE(1)
    barrier_fenced();

    // ======================= fused LSTM epilogue (padded strides) ============
    // csT/cT/hT [128][36] f32 (4608 floats each), hbT [128][40] bf16 = 64 KB
    float*  csT = (float*)lds;             // floats     0..4607
    float*  cT  = (float*)lds + 4608;      // floats  4608..9215
    float*  hT  = (float*)lds + 9216;      // floats  9216..13823
    ushort* hbT = (ushort*)lds + 27648;    // ushorts 27648..32767

    const int g = lane & 3;
    const int q = lane & 60;
    const int Mb = blkM * 128;
    const int hbase = blkN * 32;

    int hl[4]; float biasj[4];
    #pragma unroll
    for (int ni = 0; ni < 4; ++ni) {
        hl[ni] = wn * 16 + ni * 4 + (l15 >> 2);     // 0..31 (quad-uniform)
        const float* bp = (g == 0) ? bxi : (g == 1) ? bxf : (g == 2) ? bxc : bxo;
        biasj[ni] = bp[hbase + hl[ni]];
    }

    const int erow = tid >> 1;           // 0..127
    const int ecolf = (tid & 1) * 16;
    // coop-load cs tile [128][32] coalesced
    {
        const float* srcc = cs + (size_t)(Mb + erow) * H_ + hbase + ecolf;
        #pragma unroll
        for (int qq = 0; qq < 4; ++qq)
            *(float4*)&csT[erow * 36 + ecolf + qq * 4] = *(const float4*)(srcc + qq * 4);
    }
    __syncthreads();
    #pragma unroll
    for (int mi = 0; mi < 4; ++mi) {
      #pragma unroll
      for (int r = 0; r < 4; ++r) {
        const int ml = wm * 64 + mi * 16 + l4 * 4 + r;   // 0..127
        #pragma unroll
        for (int ni = 0; ni < 4; ++ni) {
            const float v = acc[mi][ni][r] + biasj[ni];
            const float gi = __shfl(v, q + 0, 64);
            const float gf = __shfl(v, q + 1, 64);
            const float gc = __shfl(v, q + 2, 64);
            const float go = __shfl(v, q + 3, 64);
            const float Ig = sigm(gi), Fg = sigm(gf);
            const float Cg = tanh_f(gc), Og = sigm(go);
            const float c_old = csT[ml * 36 + hl[ni]];
            const float c_new = Fg * c_old + Ig * Cg;
            const float h_new = Og * tanh_f(c_new);
            if (g == 0)      cT [ml * 36 + hl[ni]] = c_new;
            else if (g == 1) hT [ml * 36 + hl[ni]] = h_new;
            else if (g == 2) hbT[ml * 40 + hl[ni]] = f2bf(h_new);
        }
      }
    }
    __syncthreads();
    // coop-store coalesced
    {
        const size_t gof = (size_t)(Mb + erow) * H_ + hbase + ecolf;
        #pragma unroll
        for (int qq = 0; qq < 4; ++qq) {
            *(float4*)&cell_out[gof + qq * 4] = *(const float4*)&cT[erow * 36 + ecolf + qq * 4];
            *(float4*)&hid_out [gof + qq * 4] = *(const float4*)&hT[erow * 36 + ecolf + qq * 4];
        }
        *(uint4*)&hidB[gof]     = *(const uint4*)&hbT[erow * 40 + ecolf];
        *(uint4*)&hidB[gof + 8] = *(const uint4*)&hbT[erow * 40 + ecolf + 8];
    }
}

// ---------------------------------------------------------------------------
// GEMM2: out = hidB @ WhyB^T + b   (128x128 m97-style)
// ---------------------------------------------------------------------------
__global__ __launch_bounds__(256) void out_mm_bf16(
    const ushort* __restrict__ A, const ushort* __restrict__ Bm,
    const float* __restrict__ bw, float* __restrict__ out)
{
    __shared__ ushort As[128 * 32];
    __shared__ ushort Bs[128 * 32];
    const int tid  = threadIdx.x;
    const int lane = tid & 63;
    const int w    = tid >> 6;
    const int wm = w >> 1, wn = w & 1;
    const int blkN = blockIdx.x, blkM = blockIdx.y;
    const int srow = w * 16 + (lane >> 2);
    const int scol = (lane & 3) * 8;

    v4f acc[4][4];
    #pragma unroll
    for (int i = 0; i < 4; ++i)
      #pragma unroll
      for (int j = 0; j < 4; ++j) acc[i][j] = (v4f)0.f;

    for (int k0 = 0; k0 < H_; k0 += 32) {
        #pragma unroll
        for (int it = 0; it < 2; ++it) {
            const int row = it * 64 + srow;
            gload16(A  + (size_t)(blkM * 128 + row) * H_ + k0 + scol,
                    &As[w * 512 + it * 2048]);
            gload16(Bm + (size_t)(blkN * 128 + row) * H_ + k0 + scol,
                    &Bs[w * 512 + it * 2048]);
        }
        __syncthreads();
        v8s afr[4], bfr[4];
        #pragma unroll
        for (int i = 0; i < 4; ++i)
            afr[i] = *(const v8s*)&As[(wm * 64 + i * 16 + (lane & 15)) * 32 + (lane >> 4) * 8];
        #pragma unroll
        for (int j = 0; j < 4; ++j)
            bfr[j] = *(const v8s*)&Bs[(wn * 64 + j * 16 + (lane & 15)) * 32 + (lane >> 4) * 8];
        #pragma unroll
        for (int i = 0; i < 4; ++i)
          #pragma unroll
          for (int j = 0; j < 4; ++j)
            acc[i][j] = __builtin_amdgcn_mfma_f32_16x16x32_bf16(afr[i], bfr[j], acc[i][j], 0, 0, 0);
        __syncthreads();
    }
    #pragma unroll
    for (int i = 0; i < 4; ++i) {
      #pragma unroll
      for (int r = 0; r < 4; ++r) {
        const int m = blkM * 128 + wm * 64 + i * 16 + (lane >> 4) * 4 + r;
        #pragma unroll
        for (int j = 0; j < 4; ++j) {
            const int n = blkN * 128 + wn * 64 + j * 16 + (lane & 15);
            out[(size_t)m * O_ + n] = acc[i][j][r] + bw[n];
        }
      }
    }
}

extern "C" void kernel_launch(void* const* d_in, const int* in_sizes, int n_in,
                              void* d_out, int out_size, void* d_ws, size_t ws_size,
                              hipStream_t stream) {
    const float* x   = (const float*)d_in[0];
    const float* hs  = (const float*)d_in[1];
    const float* cs  = (const float*)d_in[2];
    const float* Wxi = (const float*)d_in[3];
    const float* bxi = (const float*)d_in[4];
    const float* Whi = (const float*)d_in[5];
    const float* Wxf = (const float*)d_in[6];
    const float* bxf = (const float*)d_in[7];
    const float* Whf = (const float*)d_in[8];
    const float* Wxc = (const float*)d_in[9];
    const float* bxc = (const float*)d_in[10];
    const float* Whc = (const float*)d_in[11];
    const float* Wxo = (const float*)d_in[12];
    const float* bxo = (const float*)d_in[13];
    const float* Who = (const float*)d_in[14];
    const float* Why = (const float*)d_in[15];
    const float* bwy = (const float*)d_in[16];

    float* out      = (float*)d_out;
    float* hid_out  = out + (size_t)B_ * O_;
    float* cell_out = hid_out + (size_t)B_ * H_;

    const size_t szW = (size_t)N1 * K1;
    const size_t szX = (size_t)B_ * K1;
    const size_t szY = (size_t)O_ * H_;

    ushort* Wcat = (ushort*)d_ws;
    ushort* Xcat = Wcat + szW;
    ushort* WhyB = Xcat + szX;
    ushort* HidB = WhyB + szY;

    convert_w<<<dim3(N1), 384, 0, stream>>>(Wxi, Whi, Wxf, Whf, Wxc, Whc, Wxo, Who, Wcat);
    convert_x<<<dim3(B_), 384, 0, stream>>>(x, hs, Xcat);
    convert_y<<<dim3(O_), 256, 0, stream>>>(Why, WhyB);

    gates_mm_128<<<dim3(N1 / 128, B_ / 128), 256, 0, stream>>>(
        Xcat, Wcat, cs, bxi, bxf, bxc, bxo, hid_out, cell_out, HidB);
    out_mm_bf16<<<dim3(O_ / 128, B_ / 128), 256, 0, stream>>>(
        HidB, WhyB, bwy, out);
}